// Round 1
// baseline (260.324 us; speedup 1.0000x reference)
//
#include <hip/hip_runtime.h>

typedef __attribute__((ext_vector_type(8))) short short8;
typedef __attribute__((ext_vector_type(4))) float f32x4;

#define D_KV   64
#define SEQ    4096
#define NBATCH 4
#define DMODEL 1024

static __device__ __forceinline__ unsigned short f32_to_bf16(float f) {
  unsigned u = __builtin_bit_cast(unsigned, f);
  u = (u + 0x7FFFu + ((u >> 16) & 1u)) >> 16;  // round-nearest-even
  return (unsigned short)u;
}

// ---------------- kernel 1: weights f32 -> bf16 (once per launch) ------------
__global__ __launch_bounds__(256) void wcvt_kernel(
    const float* __restrict__ wq, const float* __restrict__ wk,
    const float* __restrict__ wv, unsigned short* __restrict__ wbf) {
  int i = blockIdx.x * 256 + threadIdx.x;  // 0 .. 65535 (64*1024)
  wbf[i]          = f32_to_bf16(wq[i]);
  wbf[i + 65536]  = f32_to_bf16(wk[i]);
  wbf[i + 131072] = f32_to_bf16(wv[i]);
}

// ---------------- kernel 2: QKV projection ----------------------------------
// Q[t][d] scaled by 1/sqrt(64); K row-major; V stored transposed [B][64][SEQ].
__global__ __launch_bounds__(256) void qkv_proj_kernel(
    const float* __restrict__ x, const unsigned short* __restrict__ wbf,
    const float* __restrict__ bq, const float* __restrict__ bk,
    const float* __restrict__ bv,
    unsigned short* __restrict__ Q, unsigned short* __restrict__ Kt,
    unsigned short* __restrict__ VT) {
  const int lane = threadIdx.x & 63;
  const int wave = threadIdx.x >> 6;
  const int l16 = lane & 15, lq = lane >> 4;
  const long rowbase = (long)blockIdx.x * 64 + wave * 16;
  const float* xrow = x + (rowbase + l16) * DMODEL;

  f32x4 acc[12];
#pragma unroll
  for (int i = 0; i < 12; ++i) acc[i] = (f32x4){0.f, 0.f, 0.f, 0.f};

  for (int kc = 0; kc < DMODEL / 32; ++kc) {
    const int k0 = kc * 32 + lq * 8;
    short8 a;
    {
      f32x4 f0 = *reinterpret_cast<const f32x4*>(xrow + k0);
      f32x4 f1 = *reinterpret_cast<const f32x4*>(xrow + k0 + 4);
#pragma unroll
      for (int j = 0; j < 4; ++j) {
        a[j]     = (short)f32_to_bf16(f0[j]);
        a[4 + j] = (short)f32_to_bf16(f1[j]);
      }
    }
#pragma unroll
    for (int nt = 0; nt < 12; ++nt) {
      const unsigned short* wrow =
          wbf + (long)((nt >> 2) * 64 + (nt & 3) * 16 + l16) * DMODEL + k0;
      short8 b = *reinterpret_cast<const short8*>(wrow);
      acc[nt] = __builtin_amdgcn_mfma_f32_16x16x32_bf16(a, b, acc[nt], 0, 0, 0);
    }
  }

#pragma unroll
  for (int nt = 0; nt < 12; ++nt) {
    const int mat = nt >> 2;
    const int d = (nt & 3) * 16 + l16;
    const float bias = (mat == 0 ? bq : mat == 1 ? bk : bv)[d];
#pragma unroll
    for (int r = 0; r < 4; ++r) {
      const long t = rowbase + lq * 4 + r;  // C/D layout: row=(lane>>4)*4+r
      float v = acc[nt][r] + bias;
      if (mat == 0) {
        Q[t * D_KV + d] = f32_to_bf16(v * 0.125f);  // fold 1/sqrt(64)
      } else if (mat == 1) {
        Kt[t * D_KV + d] = f32_to_bf16(v);
      } else {
        const long bb = t >> 12, tt = t & 4095;
        VT[(bb * D_KV + d) * SEQ + tt] = f32_to_bf16(v);
      }
    }
  }
}

// ---------------- kernel 3: causal flash attention --------------------------
// 4 independent waves/block; wave owns one 16-row Q tile; balanced assignment.
__global__ __launch_bounds__(256) void attn_kernel(
    const unsigned short* __restrict__ Q, const unsigned short* __restrict__ Kt,
    const unsigned short* __restrict__ VT, float* __restrict__ out) {
  __shared__ __align__(16) unsigned short p_lds[4][16][72];  // +8 pad: no 16-way conflict
  const int lane = threadIdx.x & 63;
  const int wave = threadIdx.x >> 6;
  const int l16 = lane & 15, lq = lane >> 4;
  const int b = blockIdx.y;
  const int i = blockIdx.x;  // 0..63
  int tile;                  // 256 16-row tiles per batch, balanced across waves
  switch (wave) {
    case 0: tile = i; break;
    case 1: tile = 127 - i; break;
    case 2: tile = 128 + i; break;
    default: tile = 255 - i; break;
  }
  const int qbase = tile * 16;
  const long qrow = (long)b * SEQ + qbase;

  short8 qf[2];
#pragma unroll
  for (int c = 0; c < 2; ++c)
    qf[c] = *reinterpret_cast<const short8*>(Q + (qrow + l16) * D_KV + c * 32 + lq * 8);

  f32x4 o[4];
#pragma unroll
  for (int dt = 0; dt < 4; ++dt) o[dt] = (f32x4){0.f, 0.f, 0.f, 0.f};
  float m[4], ell[4];
#pragma unroll
  for (int r = 0; r < 4; ++r) { m[r] = -INFINITY; ell[r] = 0.f; }

  const int nkv = qbase / 64 + 1;  // KV tiles of 64 cols
  for (int kt = 0; kt < nkv; ++kt) {
    const int kvbase = kt * 64;
    f32x4 s[4];
#pragma unroll
    for (int ct = 0; ct < 4; ++ct) s[ct] = (f32x4){0.f, 0.f, 0.f, 0.f};
#pragma unroll
    for (int ct = 0; ct < 4; ++ct) {
      const unsigned short* krow = Kt + ((long)b * SEQ + kvbase + ct * 16 + l16) * D_KV;
#pragma unroll
      for (int c = 0; c < 2; ++c) {
        short8 kf = *reinterpret_cast<const short8*>(krow + c * 32 + lq * 8);
        s[ct] = __builtin_amdgcn_mfma_f32_16x16x32_bf16(qf[c], kf, s[ct], 0, 0, 0);
      }
    }
    if (kt == nkv - 1) {  // only the diagonal tile needs masking
#pragma unroll
      for (int ct = 0; ct < 4; ++ct) {
        const int col = kvbase + ct * 16 + l16;
#pragma unroll
        for (int r = 0; r < 4; ++r) {
          const int rowg = qbase + lq * 4 + r;
          if (col > rowg) s[ct][r] = -INFINITY;
        }
      }
    }
    float alpha[4];
#pragma unroll
    for (int r = 0; r < 4; ++r) {
      float mx = fmaxf(fmaxf(s[0][r], s[1][r]), fmaxf(s[2][r], s[3][r]));
#pragma unroll
      for (int off = 1; off < 16; off <<= 1) mx = fmaxf(mx, __shfl_xor(mx, off, 64));
      const float nm = fmaxf(m[r], mx);
      alpha[r] = __expf(m[r] - nm);  // exp(-inf)=0 on first tile
      float rs = 0.f;
#pragma unroll
      for (int ct = 0; ct < 4; ++ct) {
        float p = __expf(s[ct][r] - nm);
        s[ct][r] = p;
        rs += p;
      }
#pragma unroll
      for (int off = 1; off < 16; off <<= 1) rs += __shfl_xor(rs, off, 64);
      ell[r] = ell[r] * alpha[r] + rs;
      m[r] = nm;
    }
#pragma unroll
    for (int dt = 0; dt < 4; ++dt)
#pragma unroll
      for (int r = 0; r < 4; ++r) o[dt][r] *= alpha[r];
    // P (C-layout) -> LDS -> A-layout fragments. Per-wave buffer; same-wave DS
    // ops are HW in-order and compiler can't disprove aliasing -> no barrier.
#pragma unroll
    for (int ct = 0; ct < 4; ++ct)
#pragma unroll
      for (int r = 0; r < 4; ++r)
        p_lds[wave][lq * 4 + r][ct * 16 + l16] = f32_to_bf16(s[ct][r]);
    short8 pf[2];
#pragma unroll
    for (int c = 0; c < 2; ++c)
      pf[c] = *reinterpret_cast<const short8*>(&p_lds[wave][l16][c * 32 + lq * 8]);
#pragma unroll
    for (int dt = 0; dt < 4; ++dt) {
      const unsigned short* vrow = VT + ((long)b * D_KV + dt * 16 + l16) * SEQ + kvbase;
#pragma unroll
      for (int c = 0; c < 2; ++c) {
        short8 vf = *reinterpret_cast<const short8*>(vrow + c * 32 + lq * 8);
        o[dt] = __builtin_amdgcn_mfma_f32_16x16x32_bf16(pf[c], vf, o[dt], 0, 0, 0);
      }
    }
  }
#pragma unroll
  for (int r = 0; r < 4; ++r) {
    const float inv = 1.f / ell[r];
    float* orow = out + (qrow + lq * 4 + r) * D_KV;
#pragma unroll
    for (int dt = 0; dt < 4; ++dt) orow[dt * 16 + l16] = o[dt][r] * inv;
  }
}

// ---------------- launch ----------------------------------------------------
extern "C" void kernel_launch(void* const* d_in, const int* in_sizes, int n_in,
                              void* d_out, int out_size, void* d_ws, size_t ws_size,
                              hipStream_t stream) {
  const float* x  = (const float*)d_in[0];
  const float* wq = (const float*)d_in[1];
  const float* bq = (const float*)d_in[2];
  const float* wk = (const float*)d_in[3];
  const float* bk = (const float*)d_in[4];
  const float* wv = (const float*)d_in[5];
  const float* bv = (const float*)d_in[6];
  float* out = (float*)d_out;

  unsigned short* ws  = (unsigned short*)d_ws;
  unsigned short* wbf = ws;             // 3*64*1024        = 196608 shorts
  unsigned short* Q   = ws + 196608;    // 16384*64         = 1048576
  unsigned short* Kt  = Q + 1048576;
  unsigned short* VT  = Kt + 1048576;   // [B][64][SEQ]

  wcvt_kernel<<<256, 256, 0, stream>>>(wq, wk, wv, wbf);
  qkv_proj_kernel<<<256, 256, 0, stream>>>(x, wbf, bq, bk, bv, Q, Kt, VT);
  dim3 ag(64, NBATCH);
  attn_kernel<<<ag, 256, 0, stream>>>(Q, Kt, VT, out);
}

// Round 2
// 180.524 us; speedup vs baseline: 1.4420x; 1.4420x over previous
//
#include <hip/hip_runtime.h>

typedef __attribute__((ext_vector_type(8))) short short8;
typedef __attribute__((ext_vector_type(4))) float f32x4;

#define D_KV   64
#define SEQ    4096
#define NBATCH 4
#define DMODEL 1024

static __device__ __forceinline__ unsigned short f32_to_bf16(float f) {
  unsigned u = __builtin_bit_cast(unsigned, f);
  u = (u + 0x7FFFu + ((u >> 16) & 1u)) >> 16;  // round-nearest-even
  return (unsigned short)u;
}

// ---------------- kernel 1: weights f32 -> bf16 (once per launch) ------------
__global__ __launch_bounds__(256) void wcvt_kernel(
    const float* __restrict__ wq, const float* __restrict__ wk,
    const float* __restrict__ wv, unsigned short* __restrict__ wbf) {
  int i = blockIdx.x * 256 + threadIdx.x;  // 0 .. 65535 (64*1024)
  wbf[i]          = f32_to_bf16(wq[i]);
  wbf[i + 65536]  = f32_to_bf16(wk[i]);
  wbf[i + 131072] = f32_to_bf16(wv[i]);
}

// ---------------- kernel 2: QKV projection ----------------------------------
// Q[t][d] scaled by 1/sqrt(64); K row-major; V stored transposed [B][64][SEQ].
__global__ __launch_bounds__(256) void qkv_proj_kernel(
    const float* __restrict__ x, const unsigned short* __restrict__ wbf,
    const float* __restrict__ bq, const float* __restrict__ bk,
    const float* __restrict__ bv,
    unsigned short* __restrict__ Q, unsigned short* __restrict__ Kt,
    unsigned short* __restrict__ VT) {
  const int lane = threadIdx.x & 63;
  const int wave = threadIdx.x >> 6;
  const int l16 = lane & 15, lq = lane >> 4;
  const long rowbase = (long)blockIdx.x * 64 + wave * 16;
  const float* xrow = x + (rowbase + l16) * DMODEL;

  f32x4 acc[12];
#pragma unroll
  for (int i = 0; i < 12; ++i) acc[i] = (f32x4){0.f, 0.f, 0.f, 0.f};

  for (int kc = 0; kc < DMODEL / 32; ++kc) {
    const int k0 = kc * 32 + lq * 8;
    short8 a;
    {
      f32x4 f0 = *reinterpret_cast<const f32x4*>(xrow + k0);
      f32x4 f1 = *reinterpret_cast<const f32x4*>(xrow + k0 + 4);
#pragma unroll
      for (int j = 0; j < 4; ++j) {
        a[j]     = (short)f32_to_bf16(f0[j]);
        a[4 + j] = (short)f32_to_bf16(f1[j]);
      }
    }
#pragma unroll
    for (int nt = 0; nt < 12; ++nt) {
      const unsigned short* wrow =
          wbf + (long)((nt >> 2) * 64 + (nt & 3) * 16 + l16) * DMODEL + k0;
      short8 b = *reinterpret_cast<const short8*>(wrow);
      acc[nt] = __builtin_amdgcn_mfma_f32_16x16x32_bf16(a, b, acc[nt], 0, 0, 0);
    }
  }

#pragma unroll
  for (int nt = 0; nt < 12; ++nt) {
    const int mat = nt >> 2;
    const int d = (nt & 3) * 16 + l16;
    const float bias = (mat == 0 ? bq : mat == 1 ? bk : bv)[d];
#pragma unroll
    for (int r = 0; r < 4; ++r) {
      const long t = rowbase + lq * 4 + r;  // C/D layout: row=(lane>>4)*4+r
      float v = acc[nt][r] + bias;
      if (mat == 0) {
        Q[t * D_KV + d] = f32_to_bf16(v * 0.125f);  // fold 1/sqrt(64)
      } else if (mat == 1) {
        Kt[t * D_KV + d] = f32_to_bf16(v);
      } else {
        const long bb = t >> 12, tt = t & 4095;
        VT[(bb * D_KV + d) * SEQ + tt] = f32_to_bf16(v);
      }
    }
  }
}

// ---------------- kernel 3: causal flash attention, in-block split-K --------
// One 16-row Q tile per block; 4 waves split the KV axis round-robin
// (kt = w, w+4, ...), each with private online-softmax state; LDS combine.
__global__ __launch_bounds__(256) void attn_kernel(
    const unsigned short* __restrict__ Q, const unsigned short* __restrict__ Kt,
    const unsigned short* __restrict__ VT, float* __restrict__ out) {
  __shared__ __align__(16) unsigned short p_lds[4][16][72];  // +8 pad
  __shared__ __align__(16) float lds_o[4][16][68];           // +4 pad
  __shared__ float lds_ml[4][16][2];
  __shared__ float lds_gl[16];

  const int tid = threadIdx.x;
  const int lane = tid & 63;
  const int wave = tid >> 6;
  const int l16 = lane & 15, lq = lane >> 4;
  const int b = blockIdx.y;
  const int tile = 255 - blockIdx.x;  // heavy tiles dispatch first
  const int qbase = tile * 16;
  const long qrow = (long)b * SEQ + qbase;

  short8 qf[2];
#pragma unroll
  for (int c = 0; c < 2; ++c)
    qf[c] = *reinterpret_cast<const short8*>(Q + (qrow + l16) * D_KV + c * 32 + lq * 8);

  f32x4 o[4];
#pragma unroll
  for (int dt = 0; dt < 4; ++dt) o[dt] = (f32x4){0.f, 0.f, 0.f, 0.f};
  float m[4], ell[4];
#pragma unroll
  for (int r = 0; r < 4; ++r) { m[r] = -INFINITY; ell[r] = 0.f; }

  const int nkv = qbase / 64 + 1;  // KV tiles of 64 cols
  for (int kt = wave; kt < nkv; kt += 4) {
    const int kvbase = kt * 64;
    f32x4 s[4];
#pragma unroll
    for (int ct = 0; ct < 4; ++ct) s[ct] = (f32x4){0.f, 0.f, 0.f, 0.f};
#pragma unroll
    for (int ct = 0; ct < 4; ++ct) {
      const unsigned short* krow = Kt + ((long)b * SEQ + kvbase + ct * 16 + l16) * D_KV;
#pragma unroll
      for (int c = 0; c < 2; ++c) {
        short8 kf = *reinterpret_cast<const short8*>(krow + c * 32 + lq * 8);
        s[ct] = __builtin_amdgcn_mfma_f32_16x16x32_bf16(qf[c], kf, s[ct], 0, 0, 0);
      }
    }
    if (kt == nkv - 1) {  // only the diagonal tile needs masking
#pragma unroll
      for (int ct = 0; ct < 4; ++ct) {
        const int col = kvbase + ct * 16 + l16;
#pragma unroll
        for (int r = 0; r < 4; ++r) {
          const int rowg = qbase + lq * 4 + r;
          if (col > rowg) s[ct][r] = -INFINITY;
        }
      }
    }
    float alpha[4];
#pragma unroll
    for (int r = 0; r < 4; ++r) {
      float mx = fmaxf(fmaxf(s[0][r], s[1][r]), fmaxf(s[2][r], s[3][r]));
#pragma unroll
      for (int off = 1; off < 16; off <<= 1) mx = fmaxf(mx, __shfl_xor(mx, off, 64));
      const float nm = fmaxf(m[r], mx);
      alpha[r] = __expf(m[r] - nm);  // exp(-inf)=0 on first tile
      float rs = 0.f;
#pragma unroll
      for (int ct = 0; ct < 4; ++ct) {
        float p = __expf(s[ct][r] - nm);
        s[ct][r] = p;
        rs += p;
      }
#pragma unroll
      for (int off = 1; off < 16; off <<= 1) rs += __shfl_xor(rs, off, 64);
      ell[r] = ell[r] * alpha[r] + rs;
      m[r] = nm;
    }
#pragma unroll
    for (int dt = 0; dt < 4; ++dt)
#pragma unroll
      for (int r = 0; r < 4; ++r) o[dt][r] *= alpha[r];
    // P (C-layout) -> LDS -> A-layout fragments. Per-wave buffer; same-wave DS
    // ops are HW in-order -> no barrier needed.
#pragma unroll
    for (int ct = 0; ct < 4; ++ct)
#pragma unroll
      for (int r = 0; r < 4; ++r)
        p_lds[wave][lq * 4 + r][ct * 16 + l16] = f32_to_bf16(s[ct][r]);
    short8 pf[2];
#pragma unroll
    for (int c = 0; c < 2; ++c)
      pf[c] = *reinterpret_cast<const short8*>(&p_lds[wave][l16][c * 32 + lq * 8]);
#pragma unroll
    for (int dt = 0; dt < 4; ++dt) {
      const unsigned short* vrow = VT + ((long)b * D_KV + dt * 16 + l16) * SEQ + kvbase;
#pragma unroll
      for (int c = 0; c < 2; ++c) {
        short8 vf = *reinterpret_cast<const short8*>(vrow + c * 32 + lq * 8);
        o[dt] = __builtin_amdgcn_mfma_f32_16x16x32_bf16(pf[c], vf, o[dt], 0, 0, 0);
      }
    }
  }

  // ---- cross-wave combine: out = sum_w o_w*exp(m_w-gm) / sum_w l_w*exp(m_w-gm)
  if (l16 == 0) {
#pragma unroll
    for (int r = 0; r < 4; ++r) {
      lds_ml[wave][lq * 4 + r][0] = m[r];
      lds_ml[wave][lq * 4 + r][1] = ell[r];
    }
  }
  __syncthreads();
  float myscale[4];
#pragma unroll
  for (int r = 0; r < 4; ++r) {
    const int rr = lq * 4 + r;
    const float m0 = lds_ml[0][rr][0], m1 = lds_ml[1][rr][0];
    const float m2 = lds_ml[2][rr][0], m3 = lds_ml[3][rr][0];
    const float g = fmaxf(fmaxf(m0, m1), fmaxf(m2, m3));
    const float gl = lds_ml[0][rr][1] * __expf(m0 - g) +
                     lds_ml[1][rr][1] * __expf(m1 - g) +
                     lds_ml[2][rr][1] * __expf(m2 - g) +
                     lds_ml[3][rr][1] * __expf(m3 - g);
    myscale[r] = __expf(m[r] - g);
    if (wave == 0 && l16 == 0) lds_gl[rr] = gl;
  }
#pragma unroll
  for (int dt = 0; dt < 4; ++dt)
#pragma unroll
    for (int r = 0; r < 4; ++r)
      lds_o[wave][lq * 4 + r][dt * 16 + l16] = o[dt][r] * myscale[r];
  __syncthreads();
#pragma unroll
  for (int j = 0; j < 4; ++j) {
    const int e = tid + 256 * j;
    const int row = e >> 6, col = e & 63;
    const float s = lds_o[0][row][col] + lds_o[1][row][col] +
                    lds_o[2][row][col] + lds_o[3][row][col];
    out[(qrow + row) * D_KV + col] = s / lds_gl[row];
  }
}

// ---------------- launch ----------------------------------------------------
extern "C" void kernel_launch(void* const* d_in, const int* in_sizes, int n_in,
                              void* d_out, int out_size, void* d_ws, size_t ws_size,
                              hipStream_t stream) {
  const float* x  = (const float*)d_in[0];
  const float* wq = (const float*)d_in[1];
  const float* bq = (const float*)d_in[2];
  const float* wk = (const float*)d_in[3];
  const float* bk = (const float*)d_in[4];
  const float* wv = (const float*)d_in[5];
  const float* bv = (const float*)d_in[6];
  float* out = (float*)d_out;

  unsigned short* ws  = (unsigned short*)d_ws;
  unsigned short* wbf = ws;             // 3*64*1024        = 196608 shorts
  unsigned short* Q   = ws + 196608;    // 16384*64         = 1048576
  unsigned short* Kt  = Q + 1048576;
  unsigned short* VT  = Kt + 1048576;   // [B][64][SEQ]

  wcvt_kernel<<<256, 256, 0, stream>>>(wq, wk, wv, wbf);
  qkv_proj_kernel<<<256, 256, 0, stream>>>(x, wbf, bq, bk, bv, Q, Kt, VT);
  dim3 ag(256, NBATCH);
  attn_kernel<<<ag, 256, 0, stream>>>(Q, Kt, VT, out);
}